// Round 1
// baseline (345.162 us; speedup 1.0000x reference)
//
#include <hip/hip_runtime.h>
#include <hip/hip_bf16.h>
#include <math.h>

// Problem: B=64, S=2048, E=256, T=100 (derived from in_sizes at launch).
// vec[b,e] = sum_s softmax_s( tanh(theta@w.T [b,:] + h[b,s,:]@u) @ v ) * h[b,s,e]

#define E_DIM 256

// ---------------- Kernel 1: theta_w[b,e] = sum_t theta[b,t] * w[e,t] ----------
__global__ __launch_bounds__(E_DIM) void k_thetaw(const float* __restrict__ theta,
                                                  const float* __restrict__ w,
                                                  float* __restrict__ tw,
                                                  int T) {
    __shared__ float th[128];
    const int b = blockIdx.x;
    const int e = threadIdx.x;
    if (threadIdx.x < T) th[threadIdx.x] = theta[b * T + threadIdx.x];
    __syncthreads();
    float acc = 0.f;
    for (int t = 0; t < T; ++t) acc = fmaf(th[t], w[e * T + t], acc);
    tw[b * E_DIM + e] = acc;
}

// ---------------- Kernel 2: g[b,s] = sum_f tanh(tw[b,f] + sum_e h[b,s,e]*u[e,f]) * v[f]
// Block: 256 threads (thread = f), handles ROWS s-rows for one b.
// h row loads are wave-uniform -> scalar loads (SGPR broadcast); u loads coalesced.
#define ROWS 16
__global__ __launch_bounds__(E_DIM) void k_gate(const float* __restrict__ h,
                                                const float* __restrict__ u,
                                                const float* __restrict__ tw_,
                                                const float* __restrict__ v,
                                                float* __restrict__ g,
                                                int S) {
    const int b  = blockIdx.y;
    const int s0 = blockIdx.x * ROWS;
    const int f  = threadIdx.x;

    const float* hbase = h + ((size_t)b * S + s0) * E_DIM;

    float acc[ROWS];
#pragma unroll
    for (int i = 0; i < ROWS; ++i) acc[i] = 0.f;

    for (int e = 0; e < E_DIM; e += 4) {
        // u[e..e+3][f] : coalesced across threads; u is L2-resident (256 KB)
        const float u0 = u[(size_t)(e + 0) * E_DIM + f];
        const float u1 = u[(size_t)(e + 1) * E_DIM + f];
        const float u2 = u[(size_t)(e + 2) * E_DIM + f];
        const float u3 = u[(size_t)(e + 3) * E_DIM + f];
#pragma unroll
        for (int s = 0; s < ROWS; ++s) {
            const float4 hv = *reinterpret_cast<const float4*>(hbase + (size_t)s * E_DIM + e);
            acc[s] = fmaf(hv.x, u0, acc[s]);
            acc[s] = fmaf(hv.y, u1, acc[s]);
            acc[s] = fmaf(hv.z, u2, acc[s]);
            acc[s] = fmaf(hv.w, u3, acc[s]);
        }
    }

    const float tw = tw_[b * E_DIM + f];
    const float vf = v[f];

    __shared__ float red[4][ROWS];
    const int lane = f & 63, wid = f >> 6;
#pragma unroll
    for (int s = 0; s < ROWS; ++s) {
        float z = tanhf(acc[s] + tw) * vf;
#pragma unroll
        for (int off = 32; off > 0; off >>= 1) z += __shfl_down(z, off, 64);
        if (lane == 0) red[wid][s] = z;
    }
    __syncthreads();
    if (f < ROWS) {
        const float t = red[0][f] + red[1][f] + red[2][f] + red[3][f];
        g[(size_t)b * S + s0 + f] = t;
    }
}

// ---------------- Kernel 3: weight[b,:] = softmax(g[b,:]) over S ----------------
__global__ __launch_bounds__(256) void k_softmax(const float* __restrict__ g,
                                                 float* __restrict__ wt,
                                                 int S) {
    const int b = blockIdx.x, tid = threadIdx.x;
    const float* row = g + (size_t)b * S;
    const int lane = tid & 63, wid = tid >> 6;
    __shared__ float lds[4];

    float m = -3.4e38f;
    for (int s = tid; s < S; s += 256) m = fmaxf(m, row[s]);
#pragma unroll
    for (int off = 32; off > 0; off >>= 1) m = fmaxf(m, __shfl_xor(m, off, 64));
    if (lane == 0) lds[wid] = m;
    __syncthreads();
    m = fmaxf(fmaxf(lds[0], lds[1]), fmaxf(lds[2], lds[3]));
    __syncthreads();

    float sum = 0.f;
    for (int s = tid; s < S; s += 256) {
        const float e = __expf(row[s] - m);
        wt[(size_t)b * S + s] = e;
        sum += e;
    }
#pragma unroll
    for (int off = 32; off > 0; off >>= 1) sum += __shfl_xor(sum, off, 64);
    if (lane == 0) lds[wid] = sum;
    __syncthreads();
    sum = lds[0] + lds[1] + lds[2] + lds[3];

    const float inv = 1.f / sum;
    for (int s = tid; s < S; s += 256) wt[(size_t)b * S + s] *= inv;
}

// ---------------- Kernel 4: vec[b,e] = sum_s wt[b,s] * h[b,s,e] ----------------
// grid (4, B): 4 e-chunks of 64; block 512 threads = 8 waves splitting S.
__global__ __launch_bounds__(512) void k_vec(const float* __restrict__ h,
                                             const float* __restrict__ wt,
                                             float* __restrict__ out,
                                             int S) {
    const int b    = blockIdx.y;
    const int eloc = threadIdx.x & 63;
    const int e    = blockIdx.x * 64 + eloc;
    const int sw   = threadIdx.x >> 6;  // 0..7

    const float* hb = h + (size_t)b * S * E_DIM;
    const float* wr = wt + (size_t)b * S;

    float acc = 0.f;
#pragma unroll 8
    for (int s = sw; s < S; s += 8)
        acc = fmaf(wr[s], hb[(size_t)s * E_DIM + e], acc);

    __shared__ float red[8][64];
    red[sw][eloc] = acc;
    __syncthreads();
    if (threadIdx.x < 64) {
        float t = 0.f;
#pragma unroll
        for (int i = 0; i < 8; ++i) t += red[i][threadIdx.x];
        out[(size_t)b * E_DIM + blockIdx.x * 64 + threadIdx.x] = t;
    }
}

extern "C" void kernel_launch(void* const* d_in, const int* in_sizes, int n_in,
                              void* d_out, int out_size, void* d_ws, size_t ws_size,
                              hipStream_t stream) {
    const float* h     = (const float*)d_in[0];
    const float* theta = (const float*)d_in[1];
    const float* w     = (const float*)d_in[2];
    const float* v     = (const float*)d_in[3];
    const float* u     = (const float*)d_in[4];
    float* out = (float*)d_out;

    const int E = in_sizes[3];              // 256
    const int T = in_sizes[2] / E;          // 100
    const int B = in_sizes[1] / T;          // 64
    const int S = in_sizes[0] / (B * E);    // 2048

    float* tw = (float*)d_ws;                       // [B,E]
    float* g  = tw + (size_t)B * E;                 // [B,S]
    float* wt = g + (size_t)B * S;                  // [B,S]

    k_thetaw<<<dim3(B), dim3(E), 0, stream>>>(theta, w, tw, T);
    k_gate<<<dim3(S / ROWS, B), dim3(E), 0, stream>>>(h, u, tw, v, g, S);
    k_softmax<<<dim3(B), dim3(256), 0, stream>>>(g, wt, S);
    k_vec<<<dim3(4, B), dim3(512), 0, stream>>>(h, wt, out, S);
}

// Round 2
// 100.358 us; speedup vs baseline: 3.4393x; 3.4393x over previous
//
#include <hip/hip_runtime.h>
#include <hip/hip_bf16.h>
#include <math.h>

// vec[b,e] = sum_s softmax_s( tanh(theta@w.T [b,:] + h[b,s,:]@u) @ v ) * h[b,s,e]
// B=64, S=2048, E=256, T=100

#define E_DIM 256
#define GM 64        // s-rows per k_gate block
#define LDH 264      // padded LDS row stride for h tile (bf16 units)

typedef __bf16 bf16x8 __attribute__((ext_vector_type(8)));
typedef float  f32x4  __attribute__((ext_vector_type(4)));

__device__ __forceinline__ unsigned short f2bf(float x) {
    return __builtin_bit_cast(unsigned short, (__bf16)x);
}

// ---------------- Kernel 0: u_t[f][e] = bf16(u[e][f]) ----------------
__global__ __launch_bounds__(256) void k_transpose(const float* __restrict__ u,
                                                   unsigned short* __restrict__ u_t) {
    const int f = blockIdx.x, e = threadIdx.x;
    u_t[(size_t)f * E_DIM + e] = f2bf(u[(size_t)e * E_DIM + f]);
}

// ---------------- Kernel 1: tw[b,e] = sum_t theta[b,t] * w[e,t] ----------------
__global__ __launch_bounds__(E_DIM) void k_thetaw(const float* __restrict__ theta,
                                                  const float* __restrict__ w,
                                                  float* __restrict__ tw,
                                                  int T) {
    __shared__ float th[128];
    const int b = blockIdx.x;
    const int e = threadIdx.x;
    if (threadIdx.x < T) th[threadIdx.x] = theta[b * T + threadIdx.x];
    __syncthreads();
    float acc = 0.f;
    for (int t = 0; t < T; ++t) acc = fmaf(th[t], w[e * T + t], acc);
    tw[b * E_DIM + e] = acc;
}

// ---------------- Kernel 2 (MFMA): g[b,s] = sum_f tanh(tw[b,f] + (h@u)[s,f]) * v[f]
// Block: 256 threads = 4 waves. Block owns 64 s-rows x all 256 f.
// Wave w owns f-range [64w, 64w+64) with its u-slice held in registers (2 phases).
// h tile staged once fp32->bf16 in LDS (padded stride). K-loop is barrier-free.
__global__ __launch_bounds__(256, 2) void k_gate(const float* __restrict__ h,
                                                 const unsigned short* __restrict__ u_t,
                                                 const float* __restrict__ tw_,
                                                 const float* __restrict__ v,
                                                 float* __restrict__ g,
                                                 int S) {
    __shared__ unsigned short h_lds[GM * LDH];   // 33792 B
    __shared__ float red[4][GM];                 // 1 KB

    const int b   = blockIdx.y;
    const int s0  = blockIdx.x * GM;
    const int tid = threadIdx.x;
    const int w   = tid >> 6;      // wave 0..3
    const int l   = tid & 63;      // lane
    const int lg  = l >> 4;        // k-group 0..3
    const int lc  = l & 15;        // row/col class 0..15

    // ---- stage h rows s0..s0+63, fp32 -> bf16, coalesced ----
    const float* hb = h + ((size_t)b * S + s0) * E_DIM;
#pragma unroll
    for (int it = 0; it < 16; ++it) {
        const int row = it * 4 + (tid >> 6);
        const int col = (tid & 63) * 4;
        const float4 hv = *reinterpret_cast<const float4*>(hb + (size_t)row * E_DIM + col);
        uint2 pk;
        pk.x = (unsigned)f2bf(hv.x) | ((unsigned)f2bf(hv.y) << 16);
        pk.y = (unsigned)f2bf(hv.z) | ((unsigned)f2bf(hv.w) << 16);
        *reinterpret_cast<uint2*>(&h_lds[row * LDH + col]) = pk;
    }

    // ---- per-wave epilogue constants ----
    const int f0w = w * 64;
    float tw_f[4], v_f[4];
#pragma unroll
    for (int n = 0; n < 4; ++n) {
        const int f = f0w + n * 16 + lc;
        tw_f[n] = tw_[b * E_DIM + f];
        v_f[n]  = v[f];
    }

    f32x4 acc[4][4];
#pragma unroll
    for (int m = 0; m < 4; ++m)
#pragma unroll
        for (int n = 0; n < 4; ++n)
            acc[m][n] = (f32x4){0.f, 0.f, 0.f, 0.f};

    __syncthreads();   // h_lds ready

    // ---- K loop: 8 k-steps of 32, in 2 register phases of 4 ----
#pragma unroll
    for (int ph = 0; ph < 2; ++ph) {
        bf16x8 bf[4][4];   // [n][kk]  u-slice for this phase (registers, from L2)
#pragma unroll
        for (int n = 0; n < 4; ++n)
#pragma unroll
            for (int kk = 0; kk < 4; ++kk) {
                const int kt = ph * 4 + kk;
                const size_t off = (size_t)(f0w + n * 16 + lc) * E_DIM + kt * 32 + lg * 8;
                bf[n][kk] = *reinterpret_cast<const bf16x8*>(u_t + off);
            }
#pragma unroll
        for (int kk = 0; kk < 4; ++kk) {
            const int kt = ph * 4 + kk;
            bf16x8 af[4];
#pragma unroll
            for (int m = 0; m < 4; ++m)
                af[m] = *reinterpret_cast<const bf16x8*>(
                    &h_lds[(m * 16 + lc) * LDH + kt * 32 + lg * 8]);
#pragma unroll
            for (int m = 0; m < 4; ++m)
#pragma unroll
                for (int n = 0; n < 4; ++n)
                    acc[m][n] = __builtin_amdgcn_mfma_f32_16x16x32_bf16(
                        af[m], bf[n][kk], acc[m][n], 0, 0, 0);
        }
    }

    // ---- epilogue: tanh(z+tw)*v, sum over f ----
    float part[4][4] = {};   // [m][i]; row = m*16 + lg*4 + i, col-class lc
#pragma unroll
    for (int n = 0; n < 4; ++n)
#pragma unroll
        for (int m = 0; m < 4; ++m)
#pragma unroll
            for (int i = 0; i < 4; ++i)
                part[m][i] += tanhf(acc[m][n][i] + tw_f[n]) * v_f[n];

#pragma unroll
    for (int off = 1; off < 16; off <<= 1)
#pragma unroll
        for (int m = 0; m < 4; ++m)
#pragma unroll
            for (int i = 0; i < 4; ++i)
                part[m][i] += __shfl_xor(part[m][i], off, 64);

    if (lc == 0) {
#pragma unroll
        for (int m = 0; m < 4; ++m)
#pragma unroll
            for (int i = 0; i < 4; ++i)
                red[w][m * 16 + lg * 4 + i] = part[m][i];
    }
    __syncthreads();
    if (tid < GM) {
        const float sv = red[0][tid] + red[1][tid] + red[2][tid] + red[3][tid];
        g[(size_t)b * S + s0 + tid] = sv;
    }
}

// ---------------- Kernel 3: weight[b,:] = softmax(g[b,:]) ----------------
__global__ __launch_bounds__(256) void k_softmax(const float* __restrict__ g,
                                                 float* __restrict__ wt,
                                                 int S) {
    const int b = blockIdx.x, tid = threadIdx.x;
    const float* row = g + (size_t)b * S;
    const int lane = tid & 63, wid = tid >> 6;
    __shared__ float lds[4];

    float m = -3.4e38f;
    for (int s = tid; s < S; s += 256) m = fmaxf(m, row[s]);
#pragma unroll
    for (int off = 32; off > 0; off >>= 1) m = fmaxf(m, __shfl_xor(m, off, 64));
    if (lane == 0) lds[wid] = m;
    __syncthreads();
    m = fmaxf(fmaxf(lds[0], lds[1]), fmaxf(lds[2], lds[3]));
    __syncthreads();

    float sum = 0.f;
    for (int s = tid; s < S; s += 256) {
        const float e = __expf(row[s] - m);
        wt[(size_t)b * S + s] = e;
        sum += e;
    }
#pragma unroll
    for (int off = 32; off > 0; off >>= 1) sum += __shfl_xor(sum, off, 64);
    if (lane == 0) lds[wid] = sum;
    __syncthreads();
    sum = lds[0] + lds[1] + lds[2] + lds[3];

    const float inv = 1.f / sum;
    for (int s = tid; s < S; s += 256) wt[(size_t)b * S + s] *= inv;
}

// ---------------- Kernel 4a: part[sc][b][e] = sum_{s in chunk} wt[b,s]*h[b,s,e] ----
__global__ __launch_bounds__(256) void k_vec_part(const float* __restrict__ h,
                                                  const float* __restrict__ wt,
                                                  float* __restrict__ part,
                                                  int S, int B) {
    const int b  = blockIdx.y;
    const int sc = blockIdx.x;
    const int w  = threadIdx.x >> 6, l = threadIdx.x & 63;
    const int sbase = sc * 256 + w * 64;

    const float* hb = h + ((size_t)b * S + sbase) * E_DIM + l * 4;
    const float* wr = wt + (size_t)b * S + sbase;

    float4 a = {0.f, 0.f, 0.f, 0.f};
#pragma unroll 8
    for (int j = 0; j < 64; ++j) {
        const float ww = wr[j];
        const float4 hv = *reinterpret_cast<const float4*>(hb + (size_t)j * E_DIM);
        a.x = fmaf(ww, hv.x, a.x);
        a.y = fmaf(ww, hv.y, a.y);
        a.z = fmaf(ww, hv.z, a.z);
        a.w = fmaf(ww, hv.w, a.w);
    }

    __shared__ float red[4][E_DIM];
    *reinterpret_cast<float4*>(&red[w][l * 4]) = a;
    __syncthreads();
    const int t = threadIdx.x;
    const float sv = red[0][t] + red[1][t] + red[2][t] + red[3][t];
    part[((size_t)sc * B + b) * E_DIM + t] = sv;
}

// ---------------- Kernel 4b: out[b][e] = sum_sc part[sc][b][e] ----------------
__global__ __launch_bounds__(256) void k_vec_red(const float* __restrict__ part,
                                                 float* __restrict__ out,
                                                 int SC, int B) {
    const int b = blockIdx.x, t = threadIdx.x;
    float s = 0.f;
    for (int sc = 0; sc < SC; ++sc)
        s += part[((size_t)sc * B + b) * E_DIM + t];
    out[(size_t)b * E_DIM + t] = s;
}

extern "C" void kernel_launch(void* const* d_in, const int* in_sizes, int n_in,
                              void* d_out, int out_size, void* d_ws, size_t ws_size,
                              hipStream_t stream) {
    const float* h     = (const float*)d_in[0];
    const float* theta = (const float*)d_in[1];
    const float* w     = (const float*)d_in[2];
    const float* v     = (const float*)d_in[3];
    const float* u     = (const float*)d_in[4];
    float* out = (float*)d_out;

    const int E = in_sizes[3];              // 256
    const int T = in_sizes[2] / E;          // 100
    const int B = in_sizes[1] / T;          // 64
    const int S = in_sizes[0] / (B * E);    // 2048

    float* tw = (float*)d_ws;                                   // [B,E]
    float* g  = tw + (size_t)B * E;                             // [B,S]
    float* wt = g + (size_t)B * S;                              // [B,S]
    unsigned short* u_t = (unsigned short*)(wt + (size_t)B * S); // [E,E] bf16
    float* part = g;  // alias: SC*B*E == B*S since SC = S/256

    const int SC = S / 256;

    k_transpose<<<dim3(E), dim3(E), 0, stream>>>(u, u_t);
    k_thetaw<<<dim3(B), dim3(E), 0, stream>>>(theta, w, tw, T);
    k_gate<<<dim3(S / GM, B), dim3(256), 0, stream>>>(h, u_t, tw, v, g, S);
    k_softmax<<<dim3(B), dim3(256), 0, stream>>>(g, wt, S);
    k_vec_part<<<dim3(SC, B), dim3(256), 0, stream>>>(h, wt, part, S, B);
    k_vec_red<<<dim3(B), dim3(256), 0, stream>>>(part, out, SC, B);
}

// Round 3
// 89.761 us; speedup vs baseline: 3.8453x; 1.1181x over previous
//
#include <hip/hip_runtime.h>
#include <hip/hip_bf16.h>
#include <math.h>

// vec[b,e] = sum_s softmax_s( tanh(theta@w.T [b,:] + h[b,s,:]@u) @ v ) * h[b,s,e]
// B=64, S=2048, E=256, T=100

#define E_DIM 256
#define GM 64        // s-rows per k_gate block

typedef __bf16 bf16x8 __attribute__((ext_vector_type(8)));
typedef float  f32x4  __attribute__((ext_vector_type(4)));

__device__ __forceinline__ unsigned short f2bf(float x) {
    return __builtin_bit_cast(unsigned short, (__bf16)x);
}

// XOR-swizzle for a [64][256] bf16 tile (512 B rows): spread bits 4-6 by row&7.
// Bijective within each row; write side is wave-row-uniform (stays conflict-free);
// read side's 8-lane clusters land on 8 distinct 16B bank-groups.
__device__ __forceinline__ unsigned swz(unsigned byte) {
    return byte ^ ((((byte) >> 9) & 7) << 4);
}

// tanh(x) = 1 - 2/(exp(2x)+1); overflow-safe (rcp(inf)=0). ~6 VALU ops, err ~1e-6.
__device__ __forceinline__ float fast_tanh(float x) {
    const float e = __expf(2.0f * x);
    const float r = __builtin_amdgcn_rcpf(e + 1.0f);
    return fmaf(-2.0f, r, 1.0f);
}

// ---------------- Kernel 0: u_t[f][e] = bf16(u[e][f]) ----------------
__global__ __launch_bounds__(256) void k_transpose(const float* __restrict__ u,
                                                   unsigned short* __restrict__ u_t) {
    const int f = blockIdx.x, e = threadIdx.x;
    u_t[(size_t)f * E_DIM + e] = f2bf(u[(size_t)e * E_DIM + f]);
}

// ---------------- Kernel 1: tw[b,e] = sum_t theta[b,t] * w[e,t] ----------------
__global__ __launch_bounds__(E_DIM) void k_thetaw(const float* __restrict__ theta,
                                                  const float* __restrict__ w,
                                                  float* __restrict__ tw,
                                                  int T) {
    __shared__ float th[128];
    const int b = blockIdx.x;
    const int e = threadIdx.x;
    if (threadIdx.x < T) th[threadIdx.x] = theta[b * T + threadIdx.x];
    __syncthreads();
    float acc = 0.f;
    for (int t = 0; t < T; ++t) acc = fmaf(th[t], w[e * T + t], acc);
    tw[b * E_DIM + e] = acc;
}

// ---------------- Kernel 2 (MFMA): g[b,s] = sum_f tanh(tw[b,f] + (h@u)[s,f]) * v[f]
// Block: 256 threads = 4 waves; block owns 64 s-rows x all 256 f.
// Wave w owns f-range [64w,64w+64): u-slice register-loaded in 2 phases from L2.
// h tile staged once fp32->bf16 in XOR-swizzled LDS; K-loop is barrier-free.
__global__ __launch_bounds__(256, 4) void k_gate(const float* __restrict__ h,
                                                 const unsigned short* __restrict__ u_t,
                                                 const float* __restrict__ tw_,
                                                 const float* __restrict__ v,
                                                 float* __restrict__ g,
                                                 int S) {
    __shared__ unsigned short h_lds[GM * E_DIM];  // 32768 B, swizzled
    __shared__ float red[4][GM];                  // 1 KB

    const int b   = blockIdx.y;
    const int s0  = blockIdx.x * GM;
    const int tid = threadIdx.x;
    const int w   = tid >> 6;      // wave 0..3
    const int l   = tid & 63;      // lane
    const int lg  = l >> 4;        // k-group 0..3
    const int lc  = l & 15;        // row/col class 0..15

    // ---- stage h rows s0..s0+63, fp32 -> bf16, coalesced, swizzled LDS ----
    const float* hb = h + ((size_t)b * S + s0) * E_DIM;
    char* ldsb = (char*)h_lds;
#pragma unroll
    for (int it = 0; it < 16; ++it) {
        const int row = it * 4 + w;
        const float4 hv = *reinterpret_cast<const float4*>(hb + (size_t)row * E_DIM + l * 4);
        uint2 pk;
        pk.x = (unsigned)f2bf(hv.x) | ((unsigned)f2bf(hv.y) << 16);
        pk.y = (unsigned)f2bf(hv.z) | ((unsigned)f2bf(hv.w) << 16);
        *reinterpret_cast<uint2*>(ldsb + swz(row * 512 + l * 8)) = pk;
    }

    // ---- per-wave epilogue constants ----
    const int f0w = w * 64;
    float tw_f[4], v_f[4];
#pragma unroll
    for (int n = 0; n < 4; ++n) {
        const int f = f0w + n * 16 + lc;
        tw_f[n] = tw_[b * E_DIM + f];
        v_f[n]  = v[f];
    }

    f32x4 acc[4][4];
#pragma unroll
    for (int m = 0; m < 4; ++m)
#pragma unroll
        for (int n = 0; n < 4; ++n)
            acc[m][n] = (f32x4){0.f, 0.f, 0.f, 0.f};

    __syncthreads();   // h_lds ready

    // ---- K loop: 8 k-steps of 32, in 2 register phases of 4 ----
#pragma unroll
    for (int ph = 0; ph < 2; ++ph) {
        bf16x8 bf[4][4];   // [n][kk]  u-slice for this phase (from L2)
#pragma unroll
        for (int n = 0; n < 4; ++n)
#pragma unroll
            for (int kk = 0; kk < 4; ++kk) {
                const int kt = ph * 4 + kk;
                const size_t off = (size_t)(f0w + n * 16 + lc) * E_DIM + kt * 32 + lg * 8;
                bf[n][kk] = *reinterpret_cast<const bf16x8*>(u_t + off);
            }
#pragma unroll
        for (int kk = 0; kk < 4; ++kk) {
            const int kt = ph * 4 + kk;
            bf16x8 af[4];
#pragma unroll
            for (int m = 0; m < 4; ++m)
                af[m] = *reinterpret_cast<const bf16x8*>(
                    ldsb + swz((m * 16 + lc) * 512 + kt * 64 + lg * 16));
#pragma unroll
            for (int m = 0; m < 4; ++m)
#pragma unroll
                for (int n = 0; n < 4; ++n)
                    acc[m][n] = __builtin_amdgcn_mfma_f32_16x16x32_bf16(
                        af[m], bf[n][kk], acc[m][n], 0, 0, 0);
        }
    }

    // ---- epilogue: tanh(z+tw)*v, sum over f ----
    float part[4][4] = {};   // [m][i]; row = m*16 + lg*4 + i, col-class lc
#pragma unroll
    for (int n = 0; n < 4; ++n)
#pragma unroll
        for (int m = 0; m < 4; ++m)
#pragma unroll
            for (int i = 0; i < 4; ++i)
                part[m][i] += fast_tanh(acc[m][n][i] + tw_f[n]) * v_f[n];

#pragma unroll
    for (int off = 1; off < 16; off <<= 1)
#pragma unroll
        for (int m = 0; m < 4; ++m)
#pragma unroll
            for (int i = 0; i < 4; ++i)
                part[m][i] += __shfl_xor(part[m][i], off, 64);

    if (lc == 0) {
#pragma unroll
        for (int m = 0; m < 4; ++m)
#pragma unroll
            for (int i = 0; i < 4; ++i)
                red[w][m * 16 + lg * 4 + i] = part[m][i];
    }
    __syncthreads();
    if (tid < GM) {
        const float sv = red[0][tid] + red[1][tid] + red[2][tid] + red[3][tid];
        g[(size_t)b * S + s0 + tid] = sv;
    }
}

// ---------------- Kernel 3: weight[b,:] = softmax(g[b,:]) ----------------
__global__ __launch_bounds__(256) void k_softmax(const float* __restrict__ g,
                                                 float* __restrict__ wt,
                                                 int S) {
    const int b = blockIdx.x, tid = threadIdx.x;
    const float* row = g + (size_t)b * S;
    const int lane = tid & 63, wid = tid >> 6;
    __shared__ float lds[4];

    float m = -3.4e38f;
    for (int s = tid; s < S; s += 256) m = fmaxf(m, row[s]);
#pragma unroll
    for (int off = 32; off > 0; off >>= 1) m = fmaxf(m, __shfl_xor(m, off, 64));
    if (lane == 0) lds[wid] = m;
    __syncthreads();
    m = fmaxf(fmaxf(lds[0], lds[1]), fmaxf(lds[2], lds[3]));
    __syncthreads();

    float sum = 0.f;
    for (int s = tid; s < S; s += 256) {
        const float e = __expf(row[s] - m);
        wt[(size_t)b * S + s] = e;
        sum += e;
    }
#pragma unroll
    for (int off = 32; off > 0; off >>= 1) sum += __shfl_xor(sum, off, 64);
    if (lane == 0) lds[wid] = sum;
    __syncthreads();
    sum = lds[0] + lds[1] + lds[2] + lds[3];

    const float inv = 1.f / sum;
    for (int s = tid; s < S; s += 256) wt[(size_t)b * S + s] *= inv;
}

// ---------------- Kernel 4a: part[sc][b][e] = sum_{s in chunk} wt[b,s]*h[b,s,e] ----
__global__ __launch_bounds__(256) void k_vec_part(const float* __restrict__ h,
                                                  const float* __restrict__ wt,
                                                  float* __restrict__ part,
                                                  int S, int B) {
    const int b  = blockIdx.y;
    const int sc = blockIdx.x;
    const int w  = threadIdx.x >> 6, l = threadIdx.x & 63;
    const int sbase = sc * 256 + w * 64;

    const float* hb = h + ((size_t)b * S + sbase) * E_DIM + l * 4;
    const float* wr = wt + (size_t)b * S + sbase;

    float4 a = {0.f, 0.f, 0.f, 0.f};
#pragma unroll 8
    for (int j = 0; j < 64; ++j) {
        const float ww = wr[j];
        const float4 hv = *reinterpret_cast<const float4*>(hb + (size_t)j * E_DIM);
        a.x = fmaf(ww, hv.x, a.x);
        a.y = fmaf(ww, hv.y, a.y);
        a.z = fmaf(ww, hv.z, a.z);
        a.w = fmaf(ww, hv.w, a.w);
    }

    __shared__ float red[4][E_DIM];
    *reinterpret_cast<float4*>(&red[w][l * 4]) = a;
    __syncthreads();
    const int t = threadIdx.x;
    const float sv = red[0][t] + red[1][t] + red[2][t] + red[3][t];
    part[((size_t)sc * B + b) * E_DIM + t] = sv;
}

// ---------------- Kernel 4b: out[b][e] = sum_sc part[sc][b][e] ----------------
__global__ __launch_bounds__(256) void k_vec_red(const float* __restrict__ part,
                                                 float* __restrict__ out,
                                                 int SC, int B) {
    const int b = blockIdx.x, t = threadIdx.x;
    float s = 0.f;
    for (int sc = 0; sc < SC; ++sc)
        s += part[((size_t)sc * B + b) * E_DIM + t];
    out[(size_t)b * E_DIM + t] = s;
}

extern "C" void kernel_launch(void* const* d_in, const int* in_sizes, int n_in,
                              void* d_out, int out_size, void* d_ws, size_t ws_size,
                              hipStream_t stream) {
    const float* h     = (const float*)d_in[0];
    const float* theta = (const float*)d_in[1];
    const float* w     = (const float*)d_in[2];
    const float* v     = (const float*)d_in[3];
    const float* u     = (const float*)d_in[4];
    float* out = (float*)d_out;

    const int E = in_sizes[3];              // 256
    const int T = in_sizes[2] / E;          // 100
    const int B = in_sizes[1] / T;          // 64
    const int S = in_sizes[0] / (B * E);    // 2048

    float* tw = (float*)d_ws;                                    // [B,E]
    float* g  = tw + (size_t)B * E;                              // [B,S]
    float* wt = g + (size_t)B * S;                               // [B,S]
    unsigned short* u_t = (unsigned short*)(wt + (size_t)B * S); // [E,E] bf16
    float* part = g;  // alias: SC*B*E == B*S since SC = S/256

    const int SC = S / 256;

    k_transpose<<<dim3(E), dim3(E), 0, stream>>>(u, u_t);
    k_thetaw<<<dim3(B), dim3(E), 0, stream>>>(theta, w, tw, T);
    k_gate<<<dim3(S / GM, B), dim3(256), 0, stream>>>(h, u_t, tw, v, g, S);
    k_softmax<<<dim3(B), dim3(256), 0, stream>>>(g, wt, S);
    k_vec_part<<<dim3(SC, B), dim3(256), 0, stream>>>(h, wt, part, S, B);
    k_vec_red<<<dim3(B), dim3(256), 0, stream>>>(part, out, SC, B);
}

// Round 4
// 66.462 us; speedup vs baseline: 5.1934x; 1.3506x over previous
//
#include <hip/hip_runtime.h>
#include <hip/hip_bf16.h>
#include <math.h>

// vec[b,e] = sum_s softmax_s( tanh(theta@w.T [b,:] + h[b,s,:]@u) @ v ) * h[b,s,e]
// B=64, S=2048, E=256, T=100
// Fused flash-style: one pass over h; per-block (m, d, weighted-partial); exact merge.

#define E_DIM 256
#define GM 64        // s-rows per fused block

typedef __bf16 bf16x8 __attribute__((ext_vector_type(8)));
typedef float  f32x4  __attribute__((ext_vector_type(4)));

__device__ __forceinline__ unsigned short f2bf(float x) {
    return __builtin_bit_cast(unsigned short, (__bf16)x);
}
__device__ __forceinline__ float bf2f(unsigned short b) {
    return __builtin_bit_cast(float, (unsigned)b << 16);
}

// XOR-swizzle for a [64][256] bf16 tile (512 B rows): spread 16B-block index by row&7.
__device__ __forceinline__ unsigned swz(unsigned byte) {
    return byte ^ ((((byte) >> 9) & 7) << 4);
}

// tanh(x) = 1 - 2/(exp(2x)+1); overflow-safe (rcp(inf)=0).
__device__ __forceinline__ float fast_tanh(float x) {
    const float e = __expf(2.0f * x);
    const float r = __builtin_amdgcn_rcpf(e + 1.0f);
    return fmaf(-2.0f, r, 1.0f);
}

// ---------------- Kernel 0: u_t[f][e] = bf16(u[e][f]) ----------------
__global__ __launch_bounds__(256) void k_transpose(const float* __restrict__ u,
                                                   unsigned short* __restrict__ u_t) {
    const int f = blockIdx.x, e = threadIdx.x;
    u_t[(size_t)f * E_DIM + e] = f2bf(u[(size_t)e * E_DIM + f]);
}

// ---------------- Kernel 1: tw[b,e] = sum_t theta[b,t] * w[e,t] ----------------
__global__ __launch_bounds__(E_DIM) void k_thetaw(const float* __restrict__ theta,
                                                  const float* __restrict__ w,
                                                  float* __restrict__ tw,
                                                  int T) {
    __shared__ float th[128];
    const int b = blockIdx.x;
    const int e = threadIdx.x;
    if (threadIdx.x < T) th[threadIdx.x] = theta[b * T + threadIdx.x];
    __syncthreads();
    float acc = 0.f;
    for (int t = 0; t < T; ++t) acc = fmaf(th[t], w[e * T + t], acc);
    tw[b * E_DIM + e] = acc;
}

// ---------------- Kernel 2 (fused): per (b, s-chunk of 64):
//   g_s = sum_f tanh(tw[b,f] + (h@u)[s,f]) * v[f]      (MFMA, bf16)
//   m = max_s g_s;  ex_s = exp(g_s - m);  d = sum ex_s
//   partial[e] = sum_s ex_s * h[s,e]                   (from resident LDS tile)
__global__ __launch_bounds__(256, 4) void k_gate_fused(const float* __restrict__ h,
                                                       const unsigned short* __restrict__ u_t,
                                                       const float* __restrict__ tw_,
                                                       const float* __restrict__ v,
                                                       float* __restrict__ partial,
                                                       float* __restrict__ pm,
                                                       float* __restrict__ pd,
                                                       int S, int SC) {
    __shared__ unsigned short h_lds[GM * E_DIM];  // 32 KB, swizzled
    __shared__ float red[4][GM];                  // 1 KB
    __shared__ float exw[GM];                     // 256 B
    __shared__ float pacc[4][E_DIM];              // 4 KB

    const int b   = blockIdx.y;
    const int sc  = blockIdx.x;
    const int s0  = sc * GM;
    const int tid = threadIdx.x;
    const int w   = tid >> 6;      // wave 0..3
    const int l   = tid & 63;      // lane
    const int lg  = l >> 4;        // k-group 0..3
    const int lc  = l & 15;        // row/col class 0..15

    // ---- stage h rows s0..s0+63, fp32 -> bf16, coalesced, swizzled LDS ----
    const float* hb = h + ((size_t)b * S + s0) * E_DIM;
    char* ldsb = (char*)h_lds;
#pragma unroll
    for (int it = 0; it < 16; ++it) {
        const int row = it * 4 + w;
        const float4 hv = *reinterpret_cast<const float4*>(hb + (size_t)row * E_DIM + l * 4);
        uint2 pk;
        pk.x = (unsigned)f2bf(hv.x) | ((unsigned)f2bf(hv.y) << 16);
        pk.y = (unsigned)f2bf(hv.z) | ((unsigned)f2bf(hv.w) << 16);
        *reinterpret_cast<uint2*>(ldsb + swz(row * 512 + l * 8)) = pk;
    }

    // ---- per-wave epilogue constants ----
    const int f0w = w * 64;
    float tw_f[4], v_f[4];
#pragma unroll
    for (int n = 0; n < 4; ++n) {
        const int f = f0w + n * 16 + lc;
        tw_f[n] = tw_[b * E_DIM + f];
        v_f[n]  = v[f];
    }

    f32x4 acc[4][4];
#pragma unroll
    for (int m = 0; m < 4; ++m)
#pragma unroll
        for (int n = 0; n < 4; ++n)
            acc[m][n] = (f32x4){0.f, 0.f, 0.f, 0.f};

    __syncthreads();   // h_lds ready

    // ---- K loop: 8 k-steps of 32, in 2 register phases of 4 ----
#pragma unroll
    for (int ph = 0; ph < 2; ++ph) {
        bf16x8 bf[4][4];   // [n][kk]  u-slice for this phase (from L2)
#pragma unroll
        for (int n = 0; n < 4; ++n)
#pragma unroll
            for (int kk = 0; kk < 4; ++kk) {
                const int kt = ph * 4 + kk;
                const size_t off = (size_t)(f0w + n * 16 + lc) * E_DIM + kt * 32 + lg * 8;
                bf[n][kk] = *reinterpret_cast<const bf16x8*>(u_t + off);
            }
#pragma unroll
        for (int kk = 0; kk < 4; ++kk) {
            const int kt = ph * 4 + kk;
            bf16x8 af[4];
#pragma unroll
            for (int m = 0; m < 4; ++m)
                af[m] = *reinterpret_cast<const bf16x8*>(
                    ldsb + swz((m * 16 + lc) * 512 + kt * 64 + lg * 16));
#pragma unroll
            for (int m = 0; m < 4; ++m)
#pragma unroll
                for (int n = 0; n < 4; ++n)
                    acc[m][n] = __builtin_amdgcn_mfma_f32_16x16x32_bf16(
                        af[m], bf[n][kk], acc[m][n], 0, 0, 0);
        }
    }

    // ---- gate epilogue: tanh(z+tw)*v, sum over f (lc-classes then waves) ----
    float part[4][4] = {};   // [m][i]; row = m*16 + lg*4 + i, col-class lc
#pragma unroll
    for (int n = 0; n < 4; ++n)
#pragma unroll
        for (int m = 0; m < 4; ++m)
#pragma unroll
            for (int i = 0; i < 4; ++i)
                part[m][i] += fast_tanh(acc[m][n][i] + tw_f[n]) * v_f[n];

#pragma unroll
    for (int off = 1; off < 16; off <<= 1)
#pragma unroll
        for (int m = 0; m < 4; ++m)
#pragma unroll
            for (int i = 0; i < 4; ++i)
                part[m][i] += __shfl_xor(part[m][i], off, 64);

    if (lc == 0) {
#pragma unroll
        for (int m = 0; m < 4; ++m)
#pragma unroll
            for (int i = 0; i < 4; ++i)
                red[w][m * 16 + lg * 4 + i] = part[m][i];
    }
    __syncthreads();

    // ---- block softmax stats: wave 0 owns the 64 g values ----
    if (tid < GM) {
        const float g = red[0][tid] + red[1][tid] + red[2][tid] + red[3][tid];
        float mx = g;
#pragma unroll
        for (int off = 1; off < 64; off <<= 1)
            mx = fmaxf(mx, __shfl_xor(mx, off, 64));
        const float ex = __expf(g - mx);
        float d = ex;
#pragma unroll
        for (int off = 1; off < 64; off <<= 1)
            d += __shfl_xor(d, off, 64);
        exw[tid] = ex;
        if (tid == 0) {
            pm[(size_t)b * SC + sc] = mx;
            pd[(size_t)b * SC + sc] = d;
        }
    }
    __syncthreads();

    // ---- weighted partial: wave w sums rows w*16..w*16+15; lane owns 4 e-cols ----
    f32x4 a4 = (f32x4){0.f, 0.f, 0.f, 0.f};
#pragma unroll
    for (int j = 0; j < 16; ++j) {
        const int row = w * 16 + j;
        const float ws = exw[row];
        const uint2 hv = *reinterpret_cast<const uint2*>(ldsb + swz(row * 512 + l * 8));
        a4[0] = fmaf(ws, bf2f((unsigned short)(hv.x & 0xffff)), a4[0]);
        a4[1] = fmaf(ws, bf2f((unsigned short)(hv.x >> 16)),    a4[1]);
        a4[2] = fmaf(ws, bf2f((unsigned short)(hv.y & 0xffff)), a4[2]);
        a4[3] = fmaf(ws, bf2f((unsigned short)(hv.y >> 16)),    a4[3]);
    }
    *reinterpret_cast<f32x4*>(&pacc[w][l * 4]) = a4;
    __syncthreads();

    const float p = pacc[0][tid] + pacc[1][tid] + pacc[2][tid] + pacc[3][tid];
    partial[((size_t)b * SC + sc) * E_DIM + tid] = p;
}

// ---------------- Kernel 3: exact softmax merge across chunks ----------------
__global__ __launch_bounds__(256) void k_combine(const float* __restrict__ partial,
                                                 const float* __restrict__ pm,
                                                 const float* __restrict__ pd,
                                                 float* __restrict__ out,
                                                 int SC) {
    const int b = blockIdx.x, t = threadIdx.x;
    __shared__ float sm[64], sd[64];
    if (t < SC) {
        sm[t] = pm[(size_t)b * SC + t];
        sd[t] = pd[(size_t)b * SC + t];
    }
    __syncthreads();

    float M = -3.4e38f;
    for (int c = 0; c < SC; ++c) M = fmaxf(M, sm[c]);

    float num = 0.f, den = 0.f;
    for (int c = 0; c < SC; ++c) {
        const float s = __expf(sm[c] - M);
        den = fmaf(s, sd[c], den);
        num = fmaf(s, partial[((size_t)b * SC + c) * E_DIM + t], num);
    }
    out[(size_t)b * E_DIM + t] = num / den;
}

extern "C" void kernel_launch(void* const* d_in, const int* in_sizes, int n_in,
                              void* d_out, int out_size, void* d_ws, size_t ws_size,
                              hipStream_t stream) {
    const float* h     = (const float*)d_in[0];
    const float* theta = (const float*)d_in[1];
    const float* w     = (const float*)d_in[2];
    const float* v     = (const float*)d_in[3];
    const float* u     = (const float*)d_in[4];
    float* out = (float*)d_out;

    const int E = in_sizes[3];              // 256
    const int T = in_sizes[2] / E;          // 100
    const int B = in_sizes[1] / T;          // 64
    const int S = in_sizes[0] / (B * E);    // 2048
    const int SC = S / GM;                  // 32

    float* tw = (float*)d_ws;                                     // [B,E]
    unsigned short* u_t = (unsigned short*)(tw + (size_t)B * E);  // [E,E] bf16
    float* partial = (float*)(u_t + (size_t)E * E);               // [B,SC,E]
    float* pm = partial + (size_t)B * SC * E;                     // [B,SC]
    float* pd = pm + (size_t)B * SC;                              // [B,SC]

    k_transpose<<<dim3(E), dim3(E), 0, stream>>>(u, u_t);
    k_thetaw<<<dim3(B), dim3(E), 0, stream>>>(theta, w, tw, T);
    k_gate_fused<<<dim3(SC, B), dim3(256), 0, stream>>>(h, u_t, tw, v, partial, pm, pd, S, SC);
    k_combine<<<dim3(B), dim3(256), 0, stream>>>(partial, pm, pd, out, SC);
}

// Round 5
// 64.339 us; speedup vs baseline: 5.3647x; 1.0330x over previous
//
#include <hip/hip_runtime.h>
#include <hip/hip_bf16.h>
#include <math.h>

// vec[b,e] = sum_s softmax_s( tanh(theta@w.T [b,:] + h[b,s,:]@u) @ v ) * h[b,s,e]
// B=64, S=2048, E=256, T=100
// Fused flash-style: one pass over h; per-block (m, d, weighted-partial); exact merge.
// R5: __launch_bounds__(256,2) + full per-wave u-slice preload in registers (128 VGPR)
//     issued BEFORE h staging so L2 latency hides under the global h reads.

#define E_DIM 256
#define GM 64        // s-rows per fused block

typedef __bf16 bf16x8 __attribute__((ext_vector_type(8)));
typedef float  f32x4  __attribute__((ext_vector_type(4)));

__device__ __forceinline__ unsigned short f2bf(float x) {
    return __builtin_bit_cast(unsigned short, (__bf16)x);
}
__device__ __forceinline__ float bf2f(unsigned short b) {
    return __builtin_bit_cast(float, (unsigned)b << 16);
}

// XOR-swizzle for a [64][256] bf16 tile (512 B rows): spread 16B-slot index by row&7.
__device__ __forceinline__ unsigned swz(unsigned byte) {
    return byte ^ ((((byte) >> 9) & 7) << 4);
}

// tanh(x) = 1 - 2/(exp(2x)+1); overflow-safe (rcp(inf)=0).
__device__ __forceinline__ float fast_tanh(float x) {
    const float e = __expf(2.0f * x);
    const float r = __builtin_amdgcn_rcpf(e + 1.0f);
    return fmaf(-2.0f, r, 1.0f);
}

// ---------------- Kernel 0: u_t[f][e] = bf16(u[e][f]) ----------------
__global__ __launch_bounds__(256) void k_transpose(const float* __restrict__ u,
                                                   unsigned short* __restrict__ u_t) {
    const int f = blockIdx.x, e = threadIdx.x;
    u_t[(size_t)f * E_DIM + e] = f2bf(u[(size_t)e * E_DIM + f]);
}

// ---------------- Kernel 1: tw[b,e] = sum_t theta[b,t] * w[e,t] ----------------
__global__ __launch_bounds__(E_DIM) void k_thetaw(const float* __restrict__ theta,
                                                  const float* __restrict__ w,
                                                  float* __restrict__ tw,
                                                  int T) {
    __shared__ float th[128];
    const int b = blockIdx.x;
    const int e = threadIdx.x;
    if (threadIdx.x < T) th[threadIdx.x] = theta[b * T + threadIdx.x];
    __syncthreads();
    float acc = 0.f;
    for (int t = 0; t < T; ++t) acc = fmaf(th[t], w[e * T + t], acc);
    tw[b * E_DIM + e] = acc;
}

// ---------------- Kernel 2 (fused): per (b, s-chunk of 64):
//   g_s = sum_f tanh(tw[b,f] + (h@u)[s,f]) * v[f]      (MFMA, bf16)
//   m = max_s g_s;  ex_s = exp(g_s - m);  d = sum ex_s
//   partial[e] = sum_s ex_s * h[s,e]                   (from resident LDS tile)
__global__ __launch_bounds__(256, 2) void k_gate_fused(const float* __restrict__ h,
                                                       const unsigned short* __restrict__ u_t,
                                                       const float* __restrict__ tw_,
                                                       const float* __restrict__ v,
                                                       float* __restrict__ partial,
                                                       float* __restrict__ pm,
                                                       float* __restrict__ pd,
                                                       int S, int SC) {
    __shared__ unsigned short h_lds[GM * E_DIM];  // 32 KB, swizzled
    __shared__ float red[4][GM];                  // 1 KB
    __shared__ float exw[GM];                     // 256 B
    __shared__ float pacc[4][E_DIM];              // 4 KB

    const int b   = blockIdx.y;
    const int sc  = blockIdx.x;
    const int s0  = sc * GM;
    const int tid = threadIdx.x;
    const int w   = tid >> 6;      // wave 0..3
    const int l   = tid & 63;      // lane
    const int lg  = l >> 4;        // k-group 0..3
    const int lc  = l & 15;        // row/col class 0..15
    const int f0w = w * 64;        // wave's f-range base

    // ---- preload ENTIRE per-wave u-slice into registers (32 x bf16x8 = 128 VGPR).
    //      Issued first: L2 latency hides under the h staging below.
    bf16x8 ub[8][4];   // [kt][n]
#pragma unroll
    for (int kt = 0; kt < 8; ++kt)
#pragma unroll
        for (int n = 0; n < 4; ++n)
            ub[kt][n] = *reinterpret_cast<const bf16x8*>(
                u_t + (size_t)(f0w + n * 16 + lc) * E_DIM + kt * 32 + lg * 8);

    // ---- stage h rows s0..s0+63, fp32 -> bf16, coalesced, swizzled LDS ----
    const float* hb = h + ((size_t)b * S + s0) * E_DIM;
    char* ldsb = (char*)h_lds;
#pragma unroll
    for (int it = 0; it < 16; ++it) {
        const int row = it * 4 + w;
        const float4 hv = *reinterpret_cast<const float4*>(hb + (size_t)row * E_DIM + l * 4);
        uint2 pk;
        pk.x = (unsigned)f2bf(hv.x) | ((unsigned)f2bf(hv.y) << 16);
        pk.y = (unsigned)f2bf(hv.z) | ((unsigned)f2bf(hv.w) << 16);
        *reinterpret_cast<uint2*>(ldsb + swz(row * 512 + l * 8)) = pk;
    }

    // ---- per-wave epilogue constants ----
    float tw_f[4], v_f[4];
#pragma unroll
    for (int n = 0; n < 4; ++n) {
        const int f = f0w + n * 16 + lc;
        tw_f[n] = tw_[b * E_DIM + f];
        v_f[n]  = v[f];
    }

    f32x4 acc[4][4];
#pragma unroll
    for (int m = 0; m < 4; ++m)
#pragma unroll
        for (int n = 0; n < 4; ++n)
            acc[m][n] = (f32x4){0.f, 0.f, 0.f, 0.f};

    __syncthreads();   // h_lds ready

    // ---- K loop: 8 k-steps of 32; u already in registers, A-frags from LDS ----
#pragma unroll
    for (int kt = 0; kt < 8; ++kt) {
        bf16x8 af[4];
#pragma unroll
        for (int m = 0; m < 4; ++m)
            af[m] = *reinterpret_cast<const bf16x8*>(
                ldsb + swz((m * 16 + lc) * 512 + kt * 64 + lg * 16));
#pragma unroll
        for (int m = 0; m < 4; ++m)
#pragma unroll
            for (int n = 0; n < 4; ++n)
                acc[m][n] = __builtin_amdgcn_mfma_f32_16x16x32_bf16(
                    af[m], ub[kt][n], acc[m][n], 0, 0, 0);
    }

    // ---- gate epilogue: tanh(z+tw)*v, sum over f (lc-classes then waves) ----
    float part[4][4] = {};   // [m][i]; row = m*16 + lg*4 + i, col-class lc
#pragma unroll
    for (int n = 0; n < 4; ++n)
#pragma unroll
        for (int m = 0; m < 4; ++m)
#pragma unroll
            for (int i = 0; i < 4; ++i)
                part[m][i] += fast_tanh(acc[m][n][i] + tw_f[n]) * v_f[n];

#pragma unroll
    for (int off = 1; off < 16; off <<= 1)
#pragma unroll
        for (int m = 0; m < 4; ++m)
#pragma unroll
            for (int i = 0; i < 4; ++i)
                part[m][i] += __shfl_xor(part[m][i], off, 64);

    if (lc == 0) {
#pragma unroll
        for (int m = 0; m < 4; ++m)
#pragma unroll
            for (int i = 0; i < 4; ++i)
                red[w][m * 16 + lg * 4 + i] = part[m][i];
    }
    __syncthreads();

    // ---- block softmax stats: wave 0 owns the 64 g values ----
    if (tid < GM) {
        const float g = red[0][tid] + red[1][tid] + red[2][tid] + red[3][tid];
        float mx = g;
#pragma unroll
        for (int off = 1; off < 64; off <<= 1)
            mx = fmaxf(mx, __shfl_xor(mx, off, 64));
        const float ex = __expf(g - mx);
        float d = ex;
#pragma unroll
        for (int off = 1; off < 64; off <<= 1)
            d += __shfl_xor(d, off, 64);
        exw[tid] = ex;
        if (tid == 0) {
            pm[(size_t)b * SC + sc] = mx;
            pd[(size_t)b * SC + sc] = d;
        }
    }
    __syncthreads();

    // ---- weighted partial: wave w sums rows w*16..w*16+15; lane owns 4 e-cols ----
    f32x4 a4 = (f32x4){0.f, 0.f, 0.f, 0.f};
#pragma unroll
    for (int j = 0; j < 16; ++j) {
        const int row = w * 16 + j;
        const float ws = exw[row];
        const uint2 hv = *reinterpret_cast<const uint2*>(ldsb + swz(row * 512 + l * 8));
        a4[0] = fmaf(ws, bf2f((unsigned short)(hv.x & 0xffff)), a4[0]);
        a4[1] = fmaf(ws, bf2f((unsigned short)(hv.x >> 16)),    a4[1]);
        a4[2] = fmaf(ws, bf2f((unsigned short)(hv.y & 0xffff)), a4[2]);
        a4[3] = fmaf(ws, bf2f((unsigned short)(hv.y >> 16)),    a4[3]);
    }
    *reinterpret_cast<f32x4*>(&pacc[w][l * 4]) = a4;
    __syncthreads();

    const float p = pacc[0][tid] + pacc[1][tid] + pacc[2][tid] + pacc[3][tid];
    partial[((size_t)b * SC + sc) * E_DIM + tid] = p;
}

// ---------------- Kernel 3: exact softmax merge across chunks ----------------
__global__ __launch_bounds__(256) void k_combine(const float* __restrict__ partial,
                                                 const float* __restrict__ pm,
                                                 const float* __restrict__ pd,
                                                 float* __restrict__ out,
                                                 int SC) {
    const int b = blockIdx.x, t = threadIdx.x;
    __shared__ float sm[64], sd[64];
    if (t < SC) {
        sm[t] = pm[(size_t)b * SC + t];
        sd[t] = pd[(size_t)b * SC + t];
    }
    __syncthreads();

    float M = -3.4e38f;
    for (int c = 0; c < SC; ++c) M = fmaxf(M, sm[c]);

    float num = 0.f, den = 0.f;
    for (int c = 0; c < SC; ++c) {
        const float s = __expf(sm[c] - M);
        den = fmaf(s, sd[c], den);
        num = fmaf(s, partial[((size_t)b * SC + c) * E_DIM + t], num);
    }
    out[(size_t)b * E_DIM + t] = num / den;
}

extern "C" void kernel_launch(void* const* d_in, const int* in_sizes, int n_in,
                              void* d_out, int out_size, void* d_ws, size_t ws_size,
                              hipStream_t stream) {
    const float* h     = (const float*)d_in[0];
    const float* theta = (const float*)d_in[1];
    const float* w     = (const float*)d_in[2];
    const float* v     = (const float*)d_in[3];
    const float* u     = (const float*)d_in[4];
    float* out = (float*)d_out;

    const int E = in_sizes[3];              // 256
    const int T = in_sizes[2] / E;          // 100
    const int B = in_sizes[1] / T;          // 64
    const int S = in_sizes[0] / (B * E);    // 2048
    const int SC = S / GM;                  // 32

    float* tw = (float*)d_ws;                                     // [B,E]
    unsigned short* u_t = (unsigned short*)(tw + (size_t)B * E);  // [E,E] bf16
    float* partial = (float*)(u_t + (size_t)E * E);               // [B,SC,E]
    float* pm = partial + (size_t)B * SC * E;                     // [B,SC]
    float* pd = pm + (size_t)B * SC;                              // [B,SC]

    k_transpose<<<dim3(E), dim3(E), 0, stream>>>(u, u_t);
    k_thetaw<<<dim3(B), dim3(E), 0, stream>>>(theta, w, tw, T);
    k_gate_fused<<<dim3(SC, B), dim3(256), 0, stream>>>(h, u_t, tw, v, partial, pm, pd, S, SC);
    k_combine<<<dim3(B), dim3(256), 0, stream>>>(partial, pm, pd, out, SC);
}